// Round 11
// baseline (310.334 us; speedup 1.0000x reference)
//
#include <hip/hip_runtime.h>
#include <hip/hip_bf16.h>
#include <stdint.h>
#include <stddef.h>

#define N_PTS 100000
#define KOFF 27

typedef __attribute__((ext_vector_type(8))) __bf16 bf16x8;
typedef __attribute__((ext_vector_type(4))) float f32x4;
typedef __attribute__((ext_vector_type(8))) unsigned short ushort8;

__device__ inline unsigned short f2bf(float f) {
  union { float f; unsigned u; } x; x.f = f;
  unsigned r = x.u + 0x7fffu + ((x.u >> 16) & 1u);
  return (unsigned short)(r >> 16);
}
__device__ inline float bf2f(unsigned short b) {
  union { unsigned u; float f; } x; x.u = ((unsigned)b) << 16;
  return x.f;
}

// ---------------- prep (merged): W-reorder + feats->bf16 + zero rows/stats ----------------
// Wf[k][kk][nt][lane][j] = W[k][c = kk*32 + (lane>>4)*8 + j][d = nt*16 + (lane&15)]
__global__ __launch_bounds__(256) void prep_kernel(const float* __restrict__ feats,
                                                   const float* __restrict__ W1,
                                                   const float* __restrict__ W2,
                                                   unsigned short* __restrict__ featsb,
                                                   unsigned short* __restrict__ f2b,
                                                   unsigned short* __restrict__ wf1,
                                                   unsigned short* __restrict__ wf2,
                                                   float* __restrict__ stats) {
  __shared__ float sW[4096];
  int t = threadIdx.x;
  if (blockIdx.x < 54) {
    int which = blockIdx.x & 1;
    int k = blockIdx.x >> 1;
    const float* W = (which ? W2 : W1) + (size_t)k * 4096;
    unsigned short* wf = (which ? wf2 : wf1) + (size_t)k * 4096;
#pragma unroll
    for (int i = 0; i < 4; ++i)
      ((float4*)sW)[t + 256 * i] = ((const float4*)W)[t + 256 * i];
    __syncthreads();
#pragma unroll
    for (int i = 0; i < 16; ++i) {
      int o = i * 256 + t;
      int j = o & 7, l = (o >> 3) & 63, nt = (o >> 9) & 3, kk = (o >> 11) & 1;
      int c = kk * 32 + ((l >> 4) << 3) + j;
      int d = nt * 16 + (l & 15);
      wf[o] = f2bf(sW[c * 64 + d]);
    }
    return;
  }
  int fb = blockIdx.x - 54;
  int NB = gridDim.x - 54;
  const int NF4 = N_PTS * 16;
  for (int i = fb * 256 + t; i < NF4; i += NB * 256) {
    float4 v = ((const float4*)feats)[i];
    ushort4 o;
    o.x = f2bf(v.x); o.y = f2bf(v.y); o.z = f2bf(v.z); o.w = f2bf(v.w);
    ((ushort4*)featsb)[i] = o;
  }
  if (fb == 0) {
    if (t < 256) stats[t] = 0.f;
    uint4 z = make_uint4(0u, 0u, 0u, 0u);
    if (t < 8)            ((uint4*)(featsb + (size_t)N_PTS * 64))[t] = z;
    if (t >= 8 && t < 16) ((uint4*)(f2b    + (size_t)N_PTS * 64))[t - 8] = z;
  }
}

// ---------------- conv: gathered GEMM, B via double-buffered LDS, 16 rows/wave ----------------
#define MFMA16(a, b, c) __builtin_amdgcn_mfma_f32_16x16x32_bf16(__builtin_bit_cast(bf16x8, a), __builtin_bit_cast(bf16x8, b), c, 0, 0, 0)

// STEP k: stage B(k+1) global->reg, gather A(k+1) (iN/mN), prefetch idx/mask(k+2)
// into (iF,mF), ds_read B(k) + 8 MFMAs, reg->LDS write, barrier, flip.
#define STEP(kcur, Ac0, Ac1, An0, An1, iN, mN, iF, mF)                          \
  {                                                                             \
    const size_t kn = (size_t)((kcur) + 1) * 8192;                              \
    S0 = *(const uint4*)(wfB + kn + t16);                                       \
    S1 = *(const uint4*)(wfB + kn + 4096 + t16);                                \
    {                                                                           \
      int gie = (mN != 0.f) ? iN : N_PTS;                                       \
      const char* rp = (const char*)fin + (size_t)gie * 128 + g16;              \
      An0 = *(const uint4*)rp; An1 = *(const uint4*)(rp + 64);                  \
    }                                                                           \
    {                                                                           \
      int kf = ((kcur) + 2 <= 26) ? (kcur) + 2 : 26;                            \
      iF = idxp[(size_t)kf * N_PTS];                                            \
      float mt = mp[(size_t)kf * N_PTS]; mF = valid ? mt : 0.f;                 \
    }                                                                           \
    {                                                                           \
      const uint4* bL = (const uint4*)sB[cur];                                  \
      uint4 b0 = bL[lane],       b1 = bL[64 + lane];                            \
      uint4 b2 = bL[128 + lane], b3 = bL[192 + lane];                           \
      uint4 b4 = bL[256 + lane], b5 = bL[320 + lane];                           \
      uint4 b6 = bL[384 + lane], b7 = bL[448 + lane];                           \
      a0 = MFMA16(Ac0, b0, a0); a1 = MFMA16(Ac0, b1, a1);                       \
      a2 = MFMA16(Ac0, b2, a2); a3 = MFMA16(Ac0, b3, a3);                       \
      a0 = MFMA16(Ac1, b4, a0); a1 = MFMA16(Ac1, b5, a1);                       \
      a2 = MFMA16(Ac1, b6, a2); a3 = MFMA16(Ac1, b7, a3);                       \
    }                                                                           \
    {                                                                           \
      uint4* wL = (uint4*)sB[cur ^ 1];                                          \
      wL[t] = S0; wL[t + 256] = S1;                                             \
    }                                                                           \
    __syncthreads();                                                            \
    cur ^= 1;                                                                   \
  }

__global__ __launch_bounds__(256, 6) void conv_kernel(
    const unsigned short* __restrict__ fin,   // [N+1,64] bf16 bits; row N_PTS = zeros
    const unsigned short* __restrict__ wf,    // fragment-ordered W, bf16 bits
    const int* __restrict__ idx,              // [K,N]
    const float* __restrict__ mask,           // [K,N] in {0,1}
    unsigned short* __restrict__ yout,        // [N,64] bf16 (pre-BN)
    float* __restrict__ gsum,                 // [64]
    float* __restrict__ gsq)                  // [64]
{
  __shared__ __align__(16) unsigned char sB[2][8192];
  __shared__ float s_sum[64], s_sq[64];

  int t    = threadIdx.x;
  int lane = t & 63;
  int wid  = t >> 6;
  int m    = lane & 15;       // A gather row within 16 / C col
  int g    = lane >> 4;       // k-group 0..3
  int g16  = g * 16;
  size_t t16 = (size_t)t * 16;
  int nw   = blockIdx.x * 64 + wid * 16;   // wave's first row
  int n    = nw + m;
  bool valid = n < N_PTS;
  int nc   = valid ? n : 0;

  const int*   idxp = idx + nc;
  const float* mp   = mask + nc;
  const char*  wfB  = (const char*)wf;

  if (t < 64) { s_sum[t] = 0.f; s_sq[t] = 0.f; }

  f32x4 a0, a1, a2, a3;
#pragma unroll
  for (int r = 0; r < 4; ++r) { a0[r] = 0.f; a1[r] = 0.f; a2[r] = 0.f; a3[r] = 0.f; }

  uint4 Aa0, Aa1, Ba0, Ba1, S0, S1;
  int iA, iB; float mA, mB;
  int cur = 0;

  // ---- prologue ----
  iA = idxp[0]; { float mt = mp[0]; mA = valid ? mt : 0.f; }
  S0 = *(const uint4*)(wfB + t16);
  S1 = *(const uint4*)(wfB + 4096 + t16);
  {
    int gie = (mA != 0.f) ? iA : N_PTS;
    const char* rp = (const char*)fin + (size_t)gie * 128 + g16;
    Aa0 = *(const uint4*)rp; Aa1 = *(const uint4*)(rp + 64);
  }
  iB = idxp[N_PTS]; { float mt = mp[N_PTS]; mB = valid ? mt : 0.f; }
  {
    uint4* wL = (uint4*)sB[0];
    wL[t] = S0; wL[t + 256] = S1;
  }
  __syncthreads();

  // ---- main loop: 13 pairs cover k = 0..25 ----
  for (int kk = 0; kk < 13; ++kk) {
    int k = 2 * kk;
    STEP(k,     Aa0, Aa1,  Ba0, Ba1,  iB, mB,  iA, mA);
    STEP(k + 1, Ba0, Ba1,  Aa0, Aa1,  iA, mA,  iB, mB);
  }

  // ---- k = 26, compute only ----
  {
    const uint4* bL = (const uint4*)sB[cur];
    uint4 b0 = bL[lane],       b1 = bL[64 + lane];
    uint4 b2 = bL[128 + lane], b3 = bL[192 + lane];
    uint4 b4 = bL[256 + lane], b5 = bL[320 + lane];
    uint4 b6 = bL[384 + lane], b7 = bL[448 + lane];
    a0 = MFMA16(Aa0, b0, a0); a1 = MFMA16(Aa0, b1, a1);
    a2 = MFMA16(Aa0, b2, a2); a3 = MFMA16(Aa0, b3, a3);
    a0 = MFMA16(Aa1, b4, a0); a1 = MFMA16(Aa1, b5, a1);
    a2 = MFMA16(Aa1, b6, a2); a3 = MFMA16(Aa1, b7, a3);
  }

  // ---- write y (bf16) + fused BN stats; C/D layout (m89): col=lane&15, row=(lane>>4)*4+r
  float s0 = 0.f, q0 = 0.f, s1 = 0.f, q1 = 0.f;
  float s2 = 0.f, q2 = 0.f, s3 = 0.f, q3 = 0.f;
#pragma unroll
  for (int r = 0; r < 4; ++r) {
    int row = nw + g * 4 + r;
    float v0 = a0[r]; s0 += v0; q0 += v0 * v0;
    float v1 = a1[r]; s1 += v1; q1 += v1 * v1;
    float v2 = a2[r]; s2 += v2; q2 += v2 * v2;
    float v3 = a3[r]; s3 += v3; q3 += v3 * v3;
    if (row < N_PTS) {
      unsigned short* yr = yout + (size_t)row * 64;
      yr[m]      = f2bf(v0);
      yr[16 + m] = f2bf(v1);
      yr[32 + m] = f2bf(v2);
      yr[48 + m] = f2bf(v3);
    }
  }
  atomicAdd(&s_sum[m],      s0); atomicAdd(&s_sq[m],      q0);
  atomicAdd(&s_sum[16 + m], s1); atomicAdd(&s_sq[16 + m], q1);
  atomicAdd(&s_sum[32 + m], s2); atomicAdd(&s_sq[32 + m], q2);
  atomicAdd(&s_sum[48 + m], s3); atomicAdd(&s_sq[48 + m], q3);
  __syncthreads();
  if (t < 64) {
    atomicAdd(&gsum[t], s_sum[t]);
    atomicAdd(&gsq[t],  s_sq[t]);
  }
}

// ---------------- BN1 + ReLU: bf16 y -> bf16 out ----------------
__global__ void bn1_kernel(const unsigned short* __restrict__ y,
                           const float* __restrict__ sum,
                           const float* __restrict__ sq,
                           const float* __restrict__ gamma,
                           const float* __restrict__ beta,
                           unsigned short* __restrict__ outb) {
  __shared__ float s_scale[64], s_shift[64];
  if (threadIdx.x < 64) {
    int c = threadIdx.x;
    float mean = sum[c] * (1.f / N_PTS);
    float var  = sq[c] * (1.f / N_PTS) - mean * mean;
    float inv  = rsqrtf(var + 1e-5f);
    float sc   = gamma[c] * inv;
    s_scale[c] = sc;
    s_shift[c] = beta[c] - mean * sc;
  }
  __syncthreads();
  int tid = blockIdx.x * blockDim.x + threadIdx.x;
  int stride = gridDim.x * blockDim.x;
  const int NT = N_PTS * 8;   // short8 units
  for (int i = tid; i < NT; i += stride) {
    ushort8 v = ((const ushort8*)y)[i];
    int c = (i * 8) & 63;
    ushort8 o;
#pragma unroll
    for (int j = 0; j < 8; ++j) {
      float f = bf2f(v[j]);
      o[j] = f2bf(fmaxf(f * s_scale[c + j] + s_shift[c + j], 0.f));
    }
    ((ushort8*)outb)[i] = o;
  }
}

// ---------------- BN2 + residual + ReLU: bf16 y + f32 feats -> f32 out ----------------
__global__ void bn2_kernel(const unsigned short* __restrict__ y,
                           const float* __restrict__ sum,
                           const float* __restrict__ sq,
                           const float* __restrict__ gamma,
                           const float* __restrict__ beta,
                           const float* __restrict__ feats,
                           float* __restrict__ out) {
  __shared__ float s_scale[64], s_shift[64];
  if (threadIdx.x < 64) {
    int c = threadIdx.x;
    float mean = sum[c] * (1.f / N_PTS);
    float var  = sq[c] * (1.f / N_PTS) - mean * mean;
    float inv  = rsqrtf(var + 1e-5f);
    float sc   = gamma[c] * inv;
    s_scale[c] = sc;
    s_shift[c] = beta[c] - mean * sc;
  }
  __syncthreads();
  int tid = blockIdx.x * blockDim.x + threadIdx.x;
  int stride = gridDim.x * blockDim.x;
  const int NT = N_PTS * 8;   // 8-element units
  for (int i = tid; i < NT; i += stride) {
    ushort8 v = ((const ushort8*)y)[i];
    float4 f0 = ((const float4*)feats)[i * 2];
    float4 f1 = ((const float4*)feats)[i * 2 + 1];
    int c = (i * 8) & 63;
    float4 o0, o1;
    o0.x = fmaxf(bf2f(v[0]) * s_scale[c]     + s_shift[c]     + f0.x, 0.f);
    o0.y = fmaxf(bf2f(v[1]) * s_scale[c + 1] + s_shift[c + 1] + f0.y, 0.f);
    o0.z = fmaxf(bf2f(v[2]) * s_scale[c + 2] + s_shift[c + 2] + f0.z, 0.f);
    o0.w = fmaxf(bf2f(v[3]) * s_scale[c + 3] + s_shift[c + 3] + f0.w, 0.f);
    o1.x = fmaxf(bf2f(v[4]) * s_scale[c + 4] + s_shift[c + 4] + f1.x, 0.f);
    o1.y = fmaxf(bf2f(v[5]) * s_scale[c + 5] + s_shift[c + 5] + f1.y, 0.f);
    o1.z = fmaxf(bf2f(v[6]) * s_scale[c + 6] + s_shift[c + 6] + f1.z, 0.f);
    o1.w = fmaxf(bf2f(v[7]) * s_scale[c + 7] + s_shift[c + 7] + f1.w, 0.f);
    ((float4*)out)[i * 2]     = o0;
    ((float4*)out)[i * 2 + 1] = o1;
  }
}

// ---------------- launch ----------------
extern "C" void kernel_launch(void* const* d_in, const int* in_sizes, int n_in,
                              void* d_out, int out_size, void* d_ws, size_t ws_size,
                              hipStream_t stream) {
  const float* feats  = (const float*)d_in[0];
  const float* W1     = (const float*)d_in[1];
  const float* gamma1 = (const float*)d_in[2];
  const float* beta1  = (const float*)d_in[3];
  const float* W2     = (const float*)d_in[4];
  const float* gamma2 = (const float*)d_in[5];
  const float* beta2  = (const float*)d_in[6];
  const int*   idx1   = (const int*)d_in[7];
  const float* mask1  = (const float*)d_in[8];
  const int*   idx2   = (const int*)d_in[9];
  const float* mask2  = (const float*)d_in[10];
  float* out = (float*)d_out;

  char* ws = (char*)d_ws;
  unsigned short* featsb = (unsigned short*)(ws + 0);          // (N+1)*128 B
  unsigned short* wf1    = (unsigned short*)(ws + 12800768);   // 221,184 B
  unsigned short* wf2    = (unsigned short*)(ws + 13021952);   // 221,184 B
  float*          stats  = (float*)(ws + 13243136);            // 1,024 B
  unsigned short* f2b    = (unsigned short*)(ws + 13244160);   // (N+1)*128 B

  float* sum1 = stats;       float* sq1 = stats + 64;
  float* sum2 = stats + 128; float* sq2 = stats + 192;

  unsigned short* y1 = (unsigned short*)d_out;  // bf16 [N,64] staging in d_out (dead before bn2)
  unsigned short* y2 = featsb;                  // bf16 [N,64] staging; featsb dead after conv1

  prep_kernel<<<54 + 640, 256, 0, stream>>>(feats, W1, W2, featsb, f2b, wf1, wf2, stats);

  const int CONV_GRID = (N_PTS + 63) / 64;  // 1563
  conv_kernel<<<CONV_GRID, 256, 0, stream>>>(featsb, wf1, idx1, mask1, y1, sum1, sq1);
  bn1_kernel<<<1024, 256, 0, stream>>>(y1, sum1, sq1, gamma1, beta1, f2b);
  conv_kernel<<<CONV_GRID, 256, 0, stream>>>(f2b, wf2, idx2, mask2, y2, sum2, sq2);
  bn2_kernel<<<1024, 256, 0, stream>>>(y2, sum2, sq2, gamma2, beta2, feats, out);
}